// Round 15
// baseline (149.986 us; speedup 1.0000x reference)
//
#include <hip/hip_runtime.h>
#include <cstdint>
#include <cstddef>

#define B 4096
#define D 128
#define MARGIN_F 0.2f
#define CW 256            // per-wave candidate capacity

typedef short bf16x8 __attribute__((ext_vector_type(8)));
typedef float f32x4 __attribute__((ext_vector_type(4)));
typedef uint32_t u32x4 __attribute__((ext_vector_type(4)));

// order-preserving float->uint (ascending uint == ascending float)
__device__ __forceinline__ uint32_t xform_key(float f) {
    uint32_t u = __float_as_uint(f);
    return u ^ (uint32_t)((((int32_t)u) >> 31) | 0x80000000);
}
// decode 16-bit truncated key (bucket center under round-to-nearest encode)
__device__ __forceinline__ float unxform16(uint32_t k16) {
    uint32_t u = k16 << 16;
    u = (u & 0x80000000u) ? (u ^ 0x80000000u) : ~u;
    return __uint_as_float(u);
}
__device__ __forceinline__ unsigned short f2bf(float f) {   // round-nearest-even
    uint32_t u = __float_as_uint(f);
    return (unsigned short)((u + 0x7FFFu + ((u >> 16) & 1u)) >> 16);
}

// fused: zero out, sq[i] = ||R[i]||^2, R -> Rb (bf16 rne)
__global__ __launch_bounds__(256) void prep_kernel(const float* __restrict__ R,
                                                   float* __restrict__ sq,
                                                   unsigned short* __restrict__ Rb,
                                                   float* __restrict__ out) {
    if (blockIdx.x == 0 && threadIdx.x == 0) out[0] = 0.0f;
    int wave = threadIdx.x >> 6;
    int lane = threadIdx.x & 63;
    int row  = blockIdx.x * 4 + wave;
    const float2* R2 = (const float2*)R + (size_t)row * (D / 2);
    float2 v = R2[lane];
    ushort2 o; o.x = f2bf(v.x); o.y = f2bf(v.y);
    *(ushort2*)(Rb + (size_t)row * D + lane * 2) = o;
    float s = v.x * v.x + v.y * v.y;
#pragma unroll
    for (int off = 32; off > 0; off >>= 1) s += __shfl_down(s, off);
    if (lane == 0) sq[row] = s;
}

// r7's LDS-staged bf16 MFMA gram -> 16-bit keys (proven ~31us), with
// XCD-AFFINE index remap: by = id%32, bx = id/32 => all 32 column-blocks of
// row-panel `by` share id%8 => same XCD => each XCD's 4MB L2 holds exactly
// its 4 row-panels of keys for the consumer.
__global__ __launch_bounds__(256) void gemm_sim_mfma(const unsigned short* __restrict__ Rb,
                                                     const float* __restrict__ sq,
                                                     const int* __restrict__ labels,
                                                     unsigned short* __restrict__ simk) {
    __shared__ unsigned short sAB[32768];   // 64KB: A tile [0,16384), B tile [16384,32768)

    const int id   = blockIdx.x;
    const int Ay0  = (id % 32) * 128;       // row panel  (XCD-affine)
    const int Bx0  = (id / 32) * 128;       // col panel
    const int tid  = threadIdx.x;
    const int wid  = tid >> 6, lane = tid & 63;
    const int q    = lane >> 4, t = lane & 15;
    const int m0   = (wid >> 1) * 64;
    const int n0   = (wid & 1) * 64;

    // stage: slot s=(r<<4)|p holds global chunk (p ^ (r&15)) of row r
#pragma unroll
    for (int it = 0; it < 16; ++it) {
        int s = (wid * 16 + it) * 64 + lane;        // 0..4095
        int local = s & 2047;
        int r = local >> 4;
        int p = local & 15;
        int srcrow = ((s < 2048) ? Ay0 : Bx0) + r;
        const uint4* src = (const uint4*)(Rb + (size_t)srcrow * D + ((p ^ (r & 15)) << 3));
        *(uint4*)(&sAB[(size_t)s * 8]) = *src;
    }
    __syncthreads();

    f32x4 acc[4][4];
#pragma unroll
    for (int mi = 0; mi < 4; ++mi)
#pragma unroll
        for (int ni = 0; ni < 4; ++ni) acc[mi][ni] = (f32x4)0.0f;

#pragma unroll
    for (int kq = 0; kq < 4; ++kq) {
        bf16x8 af[4], bfr[4];
        const int ksw = (kq * 4 + q);
#pragma unroll
        for (int mi = 0; mi < 4; ++mi) {
            int r = m0 + mi * 16 + t;
            af[mi] = *(bf16x8*)(&sAB[(size_t)r * 128 + ((ksw ^ t) << 3)]);
        }
#pragma unroll
        for (int ni = 0; ni < 4; ++ni) {
            int r = n0 + ni * 16 + t;
            bfr[ni] = *(bf16x8*)(&sAB[16384 + (size_t)r * 128 + ((ksw ^ t) << 3)]);
        }
#pragma unroll
        for (int mi = 0; mi < 4; ++mi)
#pragma unroll
            for (int ni = 0; ni < 4; ++ni)
                acc[mi][ni] = __builtin_amdgcn_mfma_f32_16x16x32_bf16(
                    af[mi], bfr[ni], acc[mi][ni], 0, 0, 0);
    }

    __syncthreads();   // staging LDS dead; reuse per-wave for epilogue transpose

    const int epi0 = wid * 4608;            // 64*72 ushorts per wave
    float sqc[4]; int lc[4];
#pragma unroll
    for (int ni = 0; ni < 4; ++ni) {
        sqc[ni] = sq[Bx0 + n0 + ni * 16 + t];
        lc[ni]  = labels[Bx0 + n0 + ni * 16 + t];
    }
#pragma unroll
    for (int mi = 0; mi < 4; ++mi) {
#pragma unroll
        for (int r = 0; r < 4; ++r) {
            int lrow = mi * 16 + q * 4 + r;
            int grow = Ay0 + m0 + lrow;
            float sqr = sq[grow];
            int   lr  = labels[grow];
#pragma unroll
            for (int ni = 0; ni < 4; ++ni) {
                float g  = acc[mi][ni][r];
                float d2 = fmaxf(sqr + sqc[ni] - 2.0f * g, 0.0f);
                float dist = (d2 > 0.0f) ? sqrtf(d2) : 0.0f;
                float s = -dist + ((lr == lc[ni]) ? 0.0f : MARGIN_F);
                uint32_t key = xform_key(s);           // sim <= 0.2 -> no ovf on +0x8000
                sAB[epi0 + lrow * 72 + ni * 16 + t] =
                    (unsigned short)((key + 0x8000u) >> 16);
            }
        }
    }
#pragma unroll
    for (int it = 0; it < 8; ++it) {
        int rr = it * 8 + (lane >> 3);
        int cc = (lane & 7) * 8;
        uint4 v = *(uint4*)(&sAB[epi0 + rr * 72 + cc]);
        *(uint4*)(simk + (size_t)(Ay0 + m0 + rr) * B + Bx0 + n0 + cc) = v;
    }
}

// r7's row_loss16 (ONE WAVE PER ROW, 4 rows/block), with XCD-AFFINE row map:
// block id reads only rows from panels p with p%8 == id%8 — the panels its
// own XCD's L2 holds dirty from the producer. Inner code byte-identical r7.
__global__ __launch_bounds__(256) void row_loss16(const unsigned short* __restrict__ simk,
                                                  const int* __restrict__ labels,
                                                  float* __restrict__ out) {
    __shared__ uint32_t cand_u[4][CW];
    __shared__ int      cand_m[4][CW];
    __shared__ int      cnt_w[4];
    __shared__ float    wsum[4];

    const int wid  = threadIdx.x >> 6;
    const int lane = threadIdx.x & 63;
    const int x    = blockIdx.x & 7;        // XCD congruence class
    const int g    = blockIdx.x >> 3;       // 0..127
    const int row  = (x + 8 * (g >> 5)) * 128 + ((g & 31) * 4 + wid);

    if (lane == 0) cnt_w[wid] = 0;

    const uint4* pv = (const uint4*)(simk + (size_t)row * B);
    const int4*  lv = (const int4*)labels;
    const int li = labels[row];

    uint4 kv[8];
    uint64_t mbits = 0;
    uint32_t t1 = 0, t2 = 0;
#pragma unroll
    for (int q = 0; q < 8; ++q) {
        kv[q] = pv[q * 64 + lane];
        const int lb = (q * 64 + lane) * 2;
        int4 la = lv[lb], lc = lv[lb + 1];
        uint32_t u[8] = {kv[q].x & 0xFFFFu, kv[q].x >> 16,
                         kv[q].y & 0xFFFFu, kv[q].y >> 16,
                         kv[q].z & 0xFFFFu, kv[q].z >> 16,
                         kv[q].w & 0xFFFFu, kv[q].w >> 16};
#pragma unroll
        for (int c = 0; c < 8; ++c) {
            uint32_t mn = min(t1, u[c]);
            t1 = max(t1, u[c]);
            t2 = max(t2, mn);
        }
        mbits |= (uint64_t)(la.x == li) << (q * 8 + 0);
        mbits |= (uint64_t)(la.y == li) << (q * 8 + 1);
        mbits |= (uint64_t)(la.z == li) << (q * 8 + 2);
        mbits |= (uint64_t)(la.w == li) << (q * 8 + 3);
        mbits |= (uint64_t)(lc.x == li) << (q * 8 + 4);
        mbits |= (uint64_t)(lc.y == li) << (q * 8 + 5);
        mbits |= (uint64_t)(lc.z == li) << (q * 8 + 6);
        mbits |= (uint64_t)(lc.w == li) << (q * 8 + 7);
    }

    int kloc = __popcll(mbits);
#pragma unroll
    for (int off = 32; off > 0; off >>= 1) kloc += __shfl_xor(kloc, off);
    const int k = kloc;
    const float kf = (float)k;

    // ballot binary search: T = k-th largest of the 128-subset (<= true k-th)
    const int kneed = min(k, 128);
    uint32_t T = 0;
#pragma unroll
    for (int b = 15; b >= 0; --b) {
        uint32_t g2 = T | (1u << b);
        int c = __popcll(__ballot(t1 >= g2)) + __popcll(__ballot(t2 >= g2));
        if (c >= kneed) T = g2;
    }

    // gather candidates = {u >= T} U {matches} straight from registers
#pragma unroll
    for (int q = 0; q < 8; ++q) {
        uint32_t u[8] = {kv[q].x & 0xFFFFu, kv[q].x >> 16,
                         kv[q].y & 0xFFFFu, kv[q].y >> 16,
                         kv[q].z & 0xFFFFu, kv[q].z >> 16,
                         kv[q].w & 0xFFFFu, kv[q].w >> 16};
#pragma unroll
        for (int c = 0; c < 8; ++c) {
            int e = q * 8 + c;
            int m = (int)((mbits >> e) & 1);
            if (u[c] >= T || m) {
                int p = atomicAdd(&cnt_w[wid], 1);
                if (p < CW) {
                    cand_u[wid][p] = u[c];
                    cand_m[wid][p] = ((q * 64 + lane) * 8 + c) | (m << 12);
                }
            }
        }
    }
    const int ncand = min(cnt_w[wid], CW);

    float facc = 0.0f;

    // candidate-internal exact ranks for u >= T (every beater is a candidate)
    for (int s = lane; s < ncand; s += 64) {
        uint32_t uc = cand_u[wid][s];
        int meta = cand_m[wid][s];
        int jc = meta & 0xFFF;
        int m  = (meta >> 12) & 1;
        if (uc >= T) {
            int cnt = 0;
            for (int c = 0; c < ncand; ++c) {
                uint32_t u2 = cand_u[wid][c];
                int j2 = cand_m[wid][c] & 0xFFF;
                cnt += (u2 > uc || (u2 == uc && j2 < jc)) ? 1 : 0;
            }
            int rank = 1 + cnt;
            float v = unxform16(uc);
            if (!m && rank <= k)
                facc += v * (0.5f + ((kf - (float)rank + 1.0f) / kf) * 0.5f);
            else if (m && rank > k)
                facc -= v * (0.5f + (((float)rank - kf) / (float)(B - k)) * 0.5f);
        }
    }

    // below-T matches (rank > k guaranteed): exact global rank from registers
    for (int c = 0; c < ncand; ++c) {
        uint32_t uc = cand_u[wid][c];   // broadcast read -> wave-uniform branch
        if (uc < T) {
            int jc = cand_m[wid][c] & 0xFFF;
            int cnt = 0;
#pragma unroll
            for (int q = 0; q < 8; ++q) {
                uint32_t u[8] = {kv[q].x & 0xFFFFu, kv[q].x >> 16,
                                 kv[q].y & 0xFFFFu, kv[q].y >> 16,
                                 kv[q].z & 0xFFFFu, kv[q].z >> 16,
                                 kv[q].w & 0xFFFFu, kv[q].w >> 16};
                int jb = (q * 64 + lane) * 8;
#pragma unroll
                for (int cc = 0; cc < 8; ++cc)
                    cnt += (u[cc] > uc || (u[cc] == uc && jb + cc < jc)) ? 1 : 0;
            }
#pragma unroll
            for (int off = 32; off > 0; off >>= 1) cnt += __shfl_xor(cnt, off);
            if (lane == 0) {
                int rank = 1 + cnt;
                float v = unxform16(uc);
                facc -= v * (0.5f + (((float)rank - kf) / (float)(B - k)) * 0.5f);
            }
        }
    }

    // wave sum -> per-block combine -> one atomic per 4 rows
#pragma unroll
    for (int off = 32; off > 0; off >>= 1) facc += __shfl_xor(facc, off);
    if (lane == 0) wsum[wid] = facc;
    __syncthreads();
    if (threadIdx.x == 0)
        atomicAdd(out, wsum[0] + wsum[1] + wsum[2] + wsum[3]);
}

extern "C" void kernel_launch(void* const* d_in, const int* in_sizes, int n_in,
                              void* d_out, int out_size, void* d_ws, size_t ws_size,
                              hipStream_t stream) {
    const float* R      = (const float*)d_in[0];
    const int*   labels = (const int*)d_in[1];
    float* out = (float*)d_out;

    float*          sq   = (float*)d_ws;                                     // 16 KB
    unsigned short* Rb   = (unsigned short*)((char*)d_ws + 16 * 1024);       // 1 MB
    unsigned short* simk = (unsigned short*)((char*)d_ws + 16 * 1024 + 1024 * 1024 + 256);

    hipLaunchKernelGGL(prep_kernel, dim3(B / 4), dim3(256), 0, stream, R, sq, Rb, out);
    hipLaunchKernelGGL(gemm_sim_mfma, dim3(1024), dim3(256), 0, stream,
                       Rb, sq, labels, simk);
    hipLaunchKernelGGL(row_loss16, dim3(1024), dim3(256), 0, stream, simk, labels, out);
}